// Round 1
// baseline (657.159 us; speedup 1.0000x reference)
//
#include <hip/hip_runtime.h>

// ---- problem constants ----
#define NN 25000          // nodes
#define NE 400000         // edges
#define NGR 64            // graphs
// IN=HID=OUT=16, EF=8, EH=64, NH=128, NC=10
#define EPS 1e-5f

// ---- workspace layout (in floats) ----
// xw2 region [0, 25.6M) is dead after K2; later buffers alias into it.
static const size_t OFS_XW2  = 0;                 // N*1024
static const size_t OFS_H1   = 0;                 // N*16   (alias, written K3)
static const size_t OFS_H2   = 400000;            // N*16   (alias, written K5)
static const size_t OFS_HW   = 800000;            // N*128  (alias, written K5)
static const size_t OFS_HB   = 4000000;           // N*16   (alias, written K5)
static const size_t OFS_XB2  = 25600000;          // N*16
static const size_t OFS_AGG1 = 26000000;          // N*16
static const size_t OFS_INDEG= 26400000;          // 25600 (padded)
static const size_t OFS_AGG2 = 26425600;          // N*16
static const size_t OFS_STATS= 26825600;          // 2048
// stats: [0]sum1 [16]sumsq1 [32]scale1 [48]shift1 [64]sum2 [80]sumsq2
//        [96]scale2 [112]shift2 [128]gsum(64*16) [1152]gcnt(64)

__device__ __forceinline__ void atomAddF(float* p, float v) {
  unsafeAtomicAdd(p, v);   // HW global_atomic_add_f32 on gfx950
}

// K1: xw2[n,h,o] = sum_i x[n,i]*W2[h, i*16+o];  xb2[n,o] = sum_i x[n,i]*b2[i*16+o]
__global__ __launch_bounds__(256) void k1_xw2(const float* __restrict__ x,
    const float* __restrict__ w2, const float* __restrict__ b2,
    float* __restrict__ xw2, float* __restrict__ xb2) {
  __shared__ float w2s[64*256];
  __shared__ float b2s[256];
  __shared__ float xs[16];
  for (int idx = threadIdx.x; idx < 64*256; idx += 256) w2s[idx] = w2[idx];
  b2s[threadIdx.x] = b2[threadIdx.x];
  const int h  = threadIdx.x >> 2;
  const int og = (threadIdx.x & 3) * 4;
  for (int n = blockIdx.x; n < NN; n += gridDim.x) {
    __syncthreads();
    if (threadIdx.x < 16) xs[threadIdx.x] = x[n*16 + threadIdx.x];
    __syncthreads();
    float4 acc = {0.f,0.f,0.f,0.f};
    const float* wrow = &w2s[h*256 + og];
    #pragma unroll
    for (int i = 0; i < 16; ++i) {
      const float xi = xs[i];
      const float4 w = *reinterpret_cast<const float4*>(&wrow[i*16]);
      acc.x += xi*w.x; acc.y += xi*w.y; acc.z += xi*w.z; acc.w += xi*w.w;
    }
    *reinterpret_cast<float4*>(&xw2[(size_t)n*1024 + h*16 + og]) = acc;
    if (threadIdx.x < 16) {
      const int o = threadIdx.x;
      float a = 0.f;
      #pragma unroll
      for (int i = 0; i < 16; ++i) a += xs[i] * b2s[i*16+o];
      xb2[n*16+o] = a;
    }
  }
}

// K2: layer-1 edge pass. r=relu(ea@W1+b1); msg[o]=xb2[s,o]+sum_h r[h]*xw2[s,h,o];
//     atomic scatter into agg1[dst], count indeg[dst].
__global__ __launch_bounds__(256) void k2_edge1(const float* __restrict__ ea,
    const int* __restrict__ esrc, const int* __restrict__ edst,
    const float* __restrict__ w1, const float* __restrict__ b1,
    const float* __restrict__ xw2, const float* __restrict__ xb2,
    float* __restrict__ agg1, float* __restrict__ indeg) {
  __shared__ float w1s[8*64];
  __shared__ float b1s[64];
  __shared__ float rs[64][68];
  for (int idx = threadIdx.x; idx < 512; idx += 256) w1s[idx] = w1[idx];
  if (threadIdx.x < 64) b1s[threadIdx.x] = b1[threadIdx.x];
  const int el = threadIdx.x >> 2;
  const int q  = threadIdx.x & 3;
  const int nb = (NE + 63) >> 6;
  for (int b = blockIdx.x; b < nb; b += gridDim.x) {
    const int e0 = b << 6;
    __syncthreads();
    { // phase A: 4 threads/edge each compute 16 of the 64 r-values
      const int e = e0 + el;
      if (e < NE) {
        float eav[8];
        #pragma unroll
        for (int f = 0; f < 8; ++f) eav[f] = ea[(size_t)e*8 + f];
        #pragma unroll
        for (int hh = 0; hh < 16; ++hh) {
          const int h = q*16 + hh;
          float a = b1s[h];
          #pragma unroll
          for (int f = 0; f < 8; ++f) a += eav[f]*w1s[f*64+h];
          rs[el][h] = fmaxf(a, 0.f);
        }
      }
    }
    __syncthreads();
    { // phase B: 4 threads/edge, 4 outputs each; gather xw2[src] float4s
      const int e = e0 + el;
      if (e < NE) {
        const int s = esrc[e], d = edst[e];
        const float4* xwv = reinterpret_cast<const float4*>(&xw2[(size_t)s*1024]) + q;
        float4 m = *reinterpret_cast<const float4*>(&xb2[(size_t)s*16 + q*4]);
        #pragma unroll 8
        for (int h = 0; h < 64; ++h) {
          const float r = rs[el][h];
          const float4 t = xwv[h*4];
          m.x += r*t.x; m.y += r*t.y; m.z += r*t.z; m.w += r*t.w;
        }
        float* dst = &agg1[(size_t)d*16 + q*4];
        atomAddF(dst+0, m.x); atomAddF(dst+1, m.y);
        atomAddF(dst+2, m.z); atomAddF(dst+3, m.w);
        if (q == 0) atomAddF(&indeg[d], 1.0f);
      }
    }
  }
}

// K3: h1 = x@root1 + agg1/max(cnt,1) + bias1 ; accumulate BN1 sum/sumsq
__global__ __launch_bounds__(256) void k3_node1(const float* __restrict__ x,
    const float* __restrict__ root1, const float* __restrict__ bias1,
    const float* __restrict__ agg1, const float* __restrict__ indeg,
    float* __restrict__ h1, float* __restrict__ stats) {
  __shared__ float rt[256];
  __shared__ float red[2][16][17];
  rt[threadIdx.x] = (threadIdx.x < 256) ? root1[threadIdx.x] : 0.f;
  const int o  = threadIdx.x & 15;
  const int nl = threadIdx.x >> 4;
  const float bo = bias1[o];
  float s1 = 0.f, s2 = 0.f;
  __syncthreads();
  for (int n = blockIdx.x*16 + nl; n < NN; n += gridDim.x*16) {
    float acc = bo;
    #pragma unroll
    for (int i = 0; i < 16; ++i) acc += x[n*16+i]*rt[i*16+o];
    acc += agg1[n*16+o] / fmaxf(indeg[n], 1.0f);
    h1[n*16+o] = acc;
    s1 += acc; s2 += acc*acc;
  }
  red[0][nl][o] = s1; red[1][nl][o] = s2;
  __syncthreads();
  for (int step = 8; step > 0; step >>= 1) {
    if (nl < step) {
      red[0][nl][o] += red[0][nl+step][o];
      red[1][nl][o] += red[1][nl+step][o];
    }
    __syncthreads();
  }
  if (nl == 0) {
    atomAddF(&stats[o],      red[0][0][o]);
    atomAddF(&stats[16+o],   red[1][0][o]);
  }
}

// K4: finalize BN1 -> scale/shift
__global__ void k4_fin1(const float* __restrict__ g, const float* __restrict__ b,
                        float* __restrict__ stats) {
  const int o = threadIdx.x;
  if (o < 16) {
    const float mean = stats[o] / (float)NN;
    const float var  = stats[16+o] / (float)NN - mean*mean;
    const float sc   = g[o] * rsqrtf(var + EPS);
    stats[32+o] = sc;
    stats[48+o] = b[o] - mean*sc;
  }
}

// K5: apply BN1 (in LDS), precompute hw[n,f*16+o], hb[n,o], h2pre = hbn@root2+bias2
__global__ __launch_bounds__(256) void k5_pre2(const float* __restrict__ h1,
    const float* __restrict__ w, const float* __restrict__ bvec,
    const float* __restrict__ root2, const float* __restrict__ bias2,
    const float* __restrict__ stats,
    float* __restrict__ hw, float* __restrict__ hb, float* __restrict__ h2) {
  __shared__ float wsm[8*256];
  __shared__ float bs[256];
  __shared__ float rts[256];
  __shared__ float sc[16], sh[16], bb2[16];
  __shared__ float hn[8][17];
  for (int idx = threadIdx.x; idx < 2048; idx += 256) wsm[idx] = w[idx];
  bs[threadIdx.x]  = bvec[threadIdx.x];
  rts[threadIdx.x] = root2[threadIdx.x];
  if (threadIdx.x < 16) {
    sc[threadIdx.x]  = stats[32+threadIdx.x];
    sh[threadIdx.x]  = stats[48+threadIdx.x];
    bb2[threadIdx.x] = bias2[threadIdx.x];
  }
  const int ng = threadIdx.x >> 5;   // 0..7 node slot
  const int t  = threadIdx.x & 31;
  for (int n0 = blockIdx.x*8; n0 < NN; n0 += gridDim.x*8) {
    const int n = n0 + ng;
    __syncthreads();
    if (t < 16 && n < NN) hn[ng][t] = h1[(size_t)n*16+t]*sc[t] + sh[t];
    __syncthreads();
    if (n < NN) {
      const int fo = t*4;                    // f*16+o0
      float4 a = {0.f,0.f,0.f,0.f};
      #pragma unroll
      for (int i = 0; i < 16; ++i) {
        const float hv = hn[ng][i];
        const float4 wv = *reinterpret_cast<const float4*>(&wsm[(fo>>4)*256 + i*16 + (fo&15)]);
        a.x += hv*wv.x; a.y += hv*wv.y; a.z += hv*wv.z; a.w += hv*wv.w;
      }
      *reinterpret_cast<float4*>(&hw[(size_t)n*128 + fo]) = a;
      if (t < 16) {
        float s = 0.f;
        #pragma unroll
        for (int i = 0; i < 16; ++i) s += hn[ng][i]*bs[i*16+t];
        hb[(size_t)n*16+t] = s;
      } else {
        const int o = t - 16;
        float s = bb2[o];
        #pragma unroll
        for (int i = 0; i < 16; ++i) s += hn[ng][i]*rts[i*16+o];
        h2[(size_t)n*16+o] = s;
      }
    }
  }
}

// K6: layer-2 edge pass: msg[o] = hb[s,o] + sum_f ea[e,f]*hw[s,f*16+o]
__global__ __launch_bounds__(256) void k6_edge2(const float* __restrict__ ea,
    const int* __restrict__ esrc, const int* __restrict__ edst,
    const float* __restrict__ hw, const float* __restrict__ hb,
    float* __restrict__ agg2) {
  const int el = threadIdx.x >> 2, q = threadIdx.x & 3;
  const int nb = (NE + 63) >> 6;
  for (int b = blockIdx.x; b < nb; b += gridDim.x) {
    const int e = (b << 6) + el;
    if (e >= NE) continue;
    const int s = esrc[e], d = edst[e];
    float eav[8];
    #pragma unroll
    for (int f = 0; f < 8; ++f) eav[f] = ea[(size_t)e*8+f];
    float4 m = *reinterpret_cast<const float4*>(&hb[(size_t)s*16 + q*4]);
    const float4* hwv = reinterpret_cast<const float4*>(&hw[(size_t)s*128]) + q;
    #pragma unroll
    for (int f = 0; f < 8; ++f) {
      const float4 t = hwv[f*4];
      m.x += eav[f]*t.x; m.y += eav[f]*t.y; m.z += eav[f]*t.z; m.w += eav[f]*t.w;
    }
    float* dst = &agg2[(size_t)d*16 + q*4];
    atomAddF(dst+0,m.x); atomAddF(dst+1,m.y); atomAddF(dst+2,m.z); atomAddF(dst+3,m.w);
  }
}

// K7: h2 = h2pre + agg2/max(cnt,1); accumulate BN2 stats
__global__ __launch_bounds__(256) void k7_node2(const float* __restrict__ agg2,
    const float* __restrict__ indeg, float* __restrict__ h2, float* __restrict__ stats) {
  __shared__ float red[2][16][17];
  const int o = threadIdx.x & 15, nl = threadIdx.x >> 4;
  float s1 = 0.f, s2 = 0.f;
  for (int n = blockIdx.x*16 + nl; n < NN; n += gridDim.x*16) {
    float acc = h2[(size_t)n*16+o] + agg2[(size_t)n*16+o] / fmaxf(indeg[n], 1.0f);
    h2[(size_t)n*16+o] = acc;
    s1 += acc; s2 += acc*acc;
  }
  red[0][nl][o] = s1; red[1][nl][o] = s2;
  __syncthreads();
  for (int step = 8; step > 0; step >>= 1) {
    if (nl < step) {
      red[0][nl][o] += red[0][nl+step][o];
      red[1][nl][o] += red[1][nl+step][o];
    }
    __syncthreads();
  }
  if (nl == 0) {
    atomAddF(&stats[64+o], red[0][0][o]);
    atomAddF(&stats[80+o], red[1][0][o]);
  }
}

// K8: finalize BN2
__global__ void k8_fin2(const float* __restrict__ g, const float* __restrict__ b,
                        float* __restrict__ stats) {
  const int o = threadIdx.x;
  if (o < 16) {
    const float mean = stats[64+o] / (float)NN;
    const float var  = stats[80+o] / (float)NN - mean*mean;
    const float sc   = g[o] * rsqrtf(var + EPS);
    stats[96+o]  = sc;
    stats[112+o] = b[o] - mean*sc;
  }
}

// K9: apply BN2, pool into per-graph sums + counts
__global__ __launch_bounds__(256) void k9_pool(const float* __restrict__ h2,
    const int* __restrict__ batch, float* __restrict__ stats) {
  const int o = threadIdx.x & 15, nl = threadIdx.x >> 4;
  const float sc = stats[96+o], sh = stats[112+o];
  float* gsum = &stats[128];
  float* gcnt = &stats[1152];
  for (int n = blockIdx.x*16 + nl; n < NN; n += gridDim.x*16) {
    const float v = h2[(size_t)n*16+o]*sc + sh;
    const int g = batch[n];
    atomAddF(&gsum[g*16+o], v);
    if (o == 0) atomAddF(&gcnt[g], 1.0f);
  }
}

// K10: graph mean -> MLP head -> log_softmax
__global__ __launch_bounds__(128) void k10_head(const float* __restrict__ stats,
    const float* __restrict__ w1, const float* __restrict__ b1,
    const float* __restrict__ w2, const float* __restrict__ b2,
    float* __restrict__ out) {
  __shared__ float gm[16];
  __shared__ float a[128];
  __shared__ float l[10];
  __shared__ float mls[2];
  const int g = blockIdx.x;
  const int j = threadIdx.x;
  if (j < 16) gm[j] = stats[128 + g*16 + j] / fmaxf(stats[1152+g], 1.0f);
  __syncthreads();
  float s = b1[j];
  #pragma unroll
  for (int o = 0; o < 16; ++o) s += gm[o]*w1[o*128+j];
  a[j] = fmaxf(s, 0.f);
  __syncthreads();
  if (j < 10) {
    float t = b2[j];
    #pragma unroll 16
    for (int k = 0; k < 128; ++k) t += a[k]*w2[k*10+j];
    l[j] = t;
  }
  __syncthreads();
  if (j == 0) {
    float m = l[0];
    for (int c = 1; c < 10; ++c) m = fmaxf(m, l[c]);
    float se = 0.f;
    for (int c = 0; c < 10; ++c) se += expf(l[c]-m);
    mls[0] = m; mls[1] = logf(se);
  }
  __syncthreads();
  if (j < 10) out[g*10+j] = l[j] - mls[0] - mls[1];
}

extern "C" void kernel_launch(void* const* d_in, const int* in_sizes, int n_in,
                              void* d_out, int out_size, void* d_ws, size_t ws_size,
                              hipStream_t stream) {
  const float* x      = (const float*)d_in[0];
  const int*   esrc   = (const int*)  d_in[1];
  const int*   edst   = (const int*)  d_in[2];
  const float* ea     = (const float*)d_in[3];
  const int*   batch  = (const int*)  d_in[4];
  const float* en1_w1 = (const float*)d_in[5];
  const float* en1_b1 = (const float*)d_in[6];
  const float* en1_w2 = (const float*)d_in[7];
  const float* en1_b2 = (const float*)d_in[8];
  const float* root1  = (const float*)d_in[9];
  const float* bias1  = (const float*)d_in[10];
  const float* bn1_g  = (const float*)d_in[11];
  const float* bn1_b  = (const float*)d_in[12];
  const float* en2_w  = (const float*)d_in[13];
  const float* en2_b  = (const float*)d_in[14];
  const float* root2  = (const float*)d_in[15];
  const float* bias2  = (const float*)d_in[16];
  const float* bn2_g  = (const float*)d_in[17];
  const float* bn2_b  = (const float*)d_in[18];
  const float* mlp_w1 = (const float*)d_in[19];
  const float* mlp_b1 = (const float*)d_in[20];
  const float* mlp_w2 = (const float*)d_in[21];
  const float* mlp_b2 = (const float*)d_in[22];
  float* out = (float*)d_out;
  float* ws  = (float*)d_ws;

  float* xw2   = ws + OFS_XW2;
  float* xb2   = ws + OFS_XB2;
  float* agg1  = ws + OFS_AGG1;
  float* indeg = ws + OFS_INDEG;
  float* h1    = ws + OFS_H1;
  float* h2    = ws + OFS_H2;
  float* hw    = ws + OFS_HW;
  float* hb    = ws + OFS_HB;
  float* agg2  = ws + OFS_AGG2;
  float* stats = ws + OFS_STATS;

  hipMemsetAsync(agg1,  0, (size_t)NN*16*sizeof(float), stream);
  hipMemsetAsync(indeg, 0, (size_t)25600*sizeof(float), stream);
  hipMemsetAsync(agg2,  0, (size_t)NN*16*sizeof(float), stream);
  hipMemsetAsync(stats, 0, (size_t)2048*sizeof(float),  stream);

  hipLaunchKernelGGL(k1_xw2,  dim3(1024), dim3(256), 0, stream, x, en1_w2, en1_b2, xw2, xb2);
  hipLaunchKernelGGL(k2_edge1,dim3(2048), dim3(256), 0, stream, ea, esrc, edst, en1_w1, en1_b1,
                     xw2, xb2, agg1, indeg);
  hipLaunchKernelGGL(k3_node1,dim3(256),  dim3(256), 0, stream, x, root1, bias1, agg1, indeg, h1, stats);
  hipLaunchKernelGGL(k4_fin1, dim3(1),    dim3(64),  0, stream, bn1_g, bn1_b, stats);
  hipLaunchKernelGGL(k5_pre2, dim3(512),  dim3(256), 0, stream, h1, en2_w, en2_b, root2, bias2,
                     stats, hw, hb, h2);
  hipLaunchKernelGGL(k6_edge2,dim3(2048), dim3(256), 0, stream, ea, esrc, edst, hw, hb, agg2);
  hipLaunchKernelGGL(k7_node2,dim3(256),  dim3(256), 0, stream, agg2, indeg, h2, stats);
  hipLaunchKernelGGL(k8_fin2, dim3(1),    dim3(64),  0, stream, bn2_g, bn2_b, stats);
  hipLaunchKernelGGL(k9_pool, dim3(256),  dim3(256), 0, stream, h2, batch, stats);
  hipLaunchKernelGGL(k10_head,dim3(64),   dim3(128), 0, stream, stats, mlp_w1, mlp_b1, mlp_w2, mlp_b2, out);
}

// Round 2
// 609.916 us; speedup vs baseline: 1.0775x; 1.0775x over previous
//
#include <hip/hip_runtime.h>

// ---- problem constants ----
#define NN 25000          // nodes
#define NE 400000         // edges
#define NGR 64            // graphs
#define CHUNK 12500       // nodes per xw-buffer chunk
// IN=HID=OUT=16, EF=8, EH=64, NH=128, NC=10
#define EPS 1e-5f

// ---- workspace layout (floats) ----
// xwbuf [0, 12.8M) holds one chunk of per-node weights; dead after k2 passes,
// h1/h2 alias into it afterwards. Total footprint ~56.4 MB (proven ws >= 107MB).
static const size_t OFS_XWBUF = 0;          // CHUNK*1024 = 12,800,000
static const size_t OFS_H1    = 0;          // N*16 (alias, written K3)
static const size_t OFS_H2    = 400000;     // N*16 (alias, written K7)
static const size_t OFS_XB2   = 12800000;   // N*16
static const size_t OFS_AGG   = 13200000;   // N*16 (layer1 then re-zeroed for layer2)
static const size_t OFS_INDEG = 13600000;   // 25600 (float)
static const size_t OFS_STATS = 13625600;   // 2048 used (25600 reserved)
static const size_t OFS_ELIST = 13651200;   // NE (int)
static const size_t OFS_OFF   = 14051200;   // 25600 (int)
static const size_t OFS_OUTC  = 14076800;   // 25600 (int; reused as fill cursor)
// stats: [0]sum1 [16]sumsq1 [32]scale1 [48]shift1 [64]sum2 [80]sumsq2
//        [96]scale2 [112]shift2 [128]gsum(64*16) [1152]gcnt(64)

__device__ __forceinline__ void atomAddF(float* p, float v) {
  unsafeAtomicAdd(p, v);   // HW global_atomic_add_f32 on gfx950
}

// ---------------- CSR build ----------------
__global__ __launch_bounds__(256) void k0_hist(const int* __restrict__ esrc,
    const int* __restrict__ edst, int* __restrict__ outc, float* __restrict__ indeg) {
  for (int e = blockIdx.x*blockDim.x + threadIdx.x; e < NE; e += gridDim.x*blockDim.x) {
    atomicAdd(&outc[esrc[e]], 1);
    atomAddF(&indeg[edst[e]], 1.0f);
  }
}

__global__ __launch_bounds__(1024) void k0_scan(int* __restrict__ outc, int* __restrict__ off) {
  __shared__ int ps[1024];
  const int t = threadIdx.x;
  const int base = t * 25;            // 1024*25 = 25600 >= 25001
  int s = 0;
  for (int k = 0; k < 25; ++k) { int i = base + k; if (i < NN) s += outc[i]; }
  ps[t] = s; __syncthreads();
  for (int st = 1; st < 1024; st <<= 1) {
    int v = (t >= st) ? ps[t - st] : 0;
    __syncthreads();
    ps[t] += v;
    __syncthreads();
  }
  int run = (t > 0) ? ps[t-1] : 0;
  for (int k = 0; k < 25; ++k) {
    int i = base + k;
    if (i < NN)       { off[i] = run; run += outc[i]; outc[i] = 0; }  // zero -> cursor
    else if (i == NN) { off[i] = run; }
  }
}

__global__ __launch_bounds__(256) void k0_fill(const int* __restrict__ esrc,
    int* __restrict__ cur, const int* __restrict__ off, int* __restrict__ elist) {
  for (int e = blockIdx.x*blockDim.x + threadIdx.x; e < NE; e += gridDim.x*blockDim.x) {
    const int s = esrc[e];
    const int p = atomicAdd(&cur[s], 1);
    elist[off[s] + p] = e;
  }
}

// ---------------- K1: per-node weight precompute (chunked) ----------------
// xw[n,h,o] = sum_i x[n,i]*W2[h, i*16+o];  xb2[n,o] = sum_i x[n,i]*b2[i*16+o]
__global__ __launch_bounds__(256) void k1_xw(const float* __restrict__ x,
    const float* __restrict__ w2, const float* __restrict__ b2,
    float* __restrict__ xwbuf, float* __restrict__ xb2, int n0, int n1) {
  __shared__ float xs[16][17];
  const int t = threadIdx.x;
  const int h = t >> 2, og = (t & 3) * 4;
  const int nbase = n0 + blockIdx.x * 16;
  if (nbase >= n1) return;
  {
    const int n = nbase + (t >> 4), i = t & 15;
    xs[t >> 4][i] = (n < n1) ? x[(size_t)n*16 + i] : 0.f;
  }
  __syncthreads();
  float4 acc[16];
  #pragma unroll
  for (int n = 0; n < 16; ++n) acc[n] = make_float4(0.f,0.f,0.f,0.f);
  #pragma unroll
  for (int i = 0; i < 16; ++i) {
    const float4 w = *reinterpret_cast<const float4*>(&w2[h*256 + i*16 + og]);
    #pragma unroll
    for (int n = 0; n < 16; ++n) {
      const float xv = xs[n][i];
      acc[n].x += xv*w.x; acc[n].y += xv*w.y; acc[n].z += xv*w.z; acc[n].w += xv*w.w;
    }
  }
  #pragma unroll
  for (int n = 0; n < 16; ++n) {
    const int nn = nbase + n;
    if (nn < n1)
      *reinterpret_cast<float4*>(&xwbuf[(size_t)(nn - n0)*1024 + h*16 + og]) = acc[n];
  }
  {
    const int n = nbase + (t >> 4), o = t & 15;
    if (n < n1) {
      float s = 0.f;
      #pragma unroll
      for (int i = 0; i < 16; ++i) s += xs[t >> 4][i] * b2[i*16 + o];
      xb2[(size_t)n*16 + o] = s;
    }
  }
}

// ---------------- K2: layer-1 edge pass, CSR-by-src, xw staged in LDS ----------------
__global__ __launch_bounds__(256) void k2_csr(const float* __restrict__ ea,
    const int* __restrict__ edst,
    const float* __restrict__ w1, const float* __restrict__ b1,
    const float* __restrict__ xwbuf, const float* __restrict__ xb2,
    const int* __restrict__ off, const int* __restrict__ elist,
    float* __restrict__ agg, int n0, int n1) {
  __shared__ float w1s[512];
  __shared__ float b1s[64];
  __shared__ float xwS[4][1024];
  __shared__ float rs[4][16][68];
  for (int idx = threadIdx.x; idx < 512; idx += 256) w1s[idx] = w1[idx];
  if (threadIdx.x < 64) b1s[threadIdx.x] = b1[threadIdx.x];
  __syncthreads();
  const int lane = threadIdx.x & 63, wl = threadIdx.x >> 6;
  const int el = lane >> 2, q = lane & 3;
  const int gw = blockIdx.x*4 + wl, nw = gridDim.x*4;
  float* xw = xwS[wl];
  float (*rsw)[68] = rs[wl];

  for (int n = n0 + gw; n < n1; n += nw) {
    const int st = off[n];
    const int deg = off[n+1] - st;
    if (deg == 0) continue;
    // stage this node's 4KB xw row into LDS (coalesced, wave-private slot)
    const float4* src = reinterpret_cast<const float4*>(&xwbuf[(size_t)(n - n0)*1024]);
    #pragma unroll
    for (int j = 0; j < 4; ++j) {
      const float4 v = src[j*64 + lane];
      *reinterpret_cast<float4*>(&xw[j*256 + lane*4]) = v;
    }
    const float4 mb = *reinterpret_cast<const float4*>(&xb2[(size_t)n*16 + q*4]);
    __builtin_amdgcn_wave_barrier();

    for (int j0 = 0; j0 < deg; j0 += 16) {
      const int jj = j0 + el;
      const bool act = (jj < deg);
      const int e = act ? elist[st + jj] : elist[st];
      const int d = act ? edst[e] : 0;
      const float4 ea0 = *reinterpret_cast<const float4*>(&ea[(size_t)e*8]);
      const float4 ea1 = *reinterpret_cast<const float4*>(&ea[(size_t)e*8 + 4]);
      const float eav[8] = {ea0.x, ea0.y, ea0.z, ea0.w, ea1.x, ea1.y, ea1.z, ea1.w};
      // phase A: this lane computes r[h] for h = q*16 .. q*16+15
      #pragma unroll
      for (int g = 0; g < 4; ++g) {
        float4 r4 = *reinterpret_cast<const float4*>(&b1s[q*16 + g*4]);
        #pragma unroll
        for (int f = 0; f < 8; ++f) {
          const float4 wv = *reinterpret_cast<const float4*>(&w1s[f*64 + q*16 + g*4]);
          r4.x += eav[f]*wv.x; r4.y += eav[f]*wv.y;
          r4.z += eav[f]*wv.z; r4.w += eav[f]*wv.w;
        }
        r4.x = fmaxf(r4.x, 0.f); r4.y = fmaxf(r4.y, 0.f);
        r4.z = fmaxf(r4.z, 0.f); r4.w = fmaxf(r4.w, 0.f);
        *reinterpret_cast<float4*>(&rsw[el][q*16 + g*4]) = r4;
      }
      __builtin_amdgcn_wave_barrier();
      // phase B: msg[o-quad] = xb2 + sum_h r[h]*xw[h][o]
      float4 m = mb;
      #pragma unroll
      for (int h0 = 0; h0 < 16; ++h0) {
        const float4 rv = *reinterpret_cast<const float4*>(&rsw[el][h0*4]);
        const float4 x0 = *reinterpret_cast<const float4*>(&xw[(h0*4+0)*16 + q*4]);
        const float4 x1 = *reinterpret_cast<const float4*>(&xw[(h0*4+1)*16 + q*4]);
        const float4 x2 = *reinterpret_cast<const float4*>(&xw[(h0*4+2)*16 + q*4]);
        const float4 x3 = *reinterpret_cast<const float4*>(&xw[(h0*4+3)*16 + q*4]);
        m.x += rv.x*x0.x + rv.y*x1.x + rv.z*x2.x + rv.w*x3.x;
        m.y += rv.x*x0.y + rv.y*x1.y + rv.z*x2.y + rv.w*x3.y;
        m.z += rv.x*x0.z + rv.y*x1.z + rv.z*x2.z + rv.w*x3.z;
        m.w += rv.x*x0.w + rv.y*x1.w + rv.z*x2.w + rv.w*x3.w;
      }
      if (act) {
        float* dst = &agg[(size_t)d*16 + q*4];
        atomAddF(dst+0, m.x); atomAddF(dst+1, m.y);
        atomAddF(dst+2, m.z); atomAddF(dst+3, m.w);
      }
      __builtin_amdgcn_wave_barrier();
    }
  }
}

// ---------------- K3: h1 = x@root1 + agg/max(indeg,1) + bias1; BN1 stats ----------------
__global__ __launch_bounds__(256) void k3_node1(const float* __restrict__ x,
    const float* __restrict__ root1, const float* __restrict__ bias1,
    const float* __restrict__ agg, const float* __restrict__ indeg,
    float* __restrict__ h1, float* __restrict__ stats) {
  __shared__ float rt[256];
  __shared__ float red[2][16][17];
  rt[threadIdx.x] = root1[threadIdx.x];
  const int o = threadIdx.x & 15, nl = threadIdx.x >> 4;
  const float bo = bias1[o];
  float s1 = 0.f, s2 = 0.f;
  __syncthreads();
  for (int n = blockIdx.x*16 + nl; n < NN; n += gridDim.x*16) {
    float acc = bo;
    #pragma unroll
    for (int i = 0; i < 16; ++i) acc += x[(size_t)n*16 + i] * rt[i*16 + o];
    acc += agg[(size_t)n*16 + o] / fmaxf(indeg[n], 1.0f);
    h1[(size_t)n*16 + o] = acc;
    s1 += acc; s2 += acc*acc;
  }
  red[0][nl][o] = s1; red[1][nl][o] = s2;
  __syncthreads();
  for (int step = 8; step > 0; step >>= 1) {
    if (nl < step) {
      red[0][nl][o] += red[0][nl+step][o];
      red[1][nl][o] += red[1][nl+step][o];
    }
    __syncthreads();
  }
  if (nl == 0) { atomAddF(&stats[o], red[0][0][o]); atomAddF(&stats[16+o], red[1][0][o]); }
}

__global__ void k4_fin1(const float* __restrict__ g, const float* __restrict__ b,
                        float* __restrict__ stats) {
  const int o = threadIdx.x;
  if (o < 16) {
    const float mean = stats[o] / (float)NN;
    const float var  = stats[16+o] / (float)NN - mean*mean;
    const float sc   = g[o] * rsqrtf(var + EPS);
    stats[32+o] = sc;
    stats[48+o] = b[o] - mean*sc;
  }
}

// ---------------- K6: layer-2 edge pass, CSR-by-src, hw computed per node ----------------
__global__ __launch_bounds__(256) void k6_csr(const float* __restrict__ ea,
    const int* __restrict__ edst,
    const float* __restrict__ h1, const float* __restrict__ stats,
    const float* __restrict__ w, const float* __restrict__ bvec,
    const int* __restrict__ off, const int* __restrict__ elist,
    float* __restrict__ agg) {
  __shared__ float ws2[2048];
  __shared__ float bs2[256];
  __shared__ float hwS[4][128];
  __shared__ float hbS[4][32];   // [0..15] hbn, [16..31] hb
  for (int idx = threadIdx.x; idx < 2048; idx += 256) ws2[idx] = w[idx];
  bs2[threadIdx.x] = bvec[threadIdx.x];
  __syncthreads();
  const int lane = threadIdx.x & 63, wl = threadIdx.x >> 6;
  const int el = lane >> 2, q = lane & 3;
  const int f = lane >> 3, o2 = (lane & 7) * 2;
  const int gw = blockIdx.x*4 + wl, nw = gridDim.x*4;
  for (int n = gw; n < NN; n += nw) {
    const int st = off[n];
    const int deg = off[n+1] - st;
    if (deg == 0) continue;
    if (lane < 16)
      hbS[wl][lane] = h1[(size_t)n*16 + lane]*stats[32+lane] + stats[48+lane];
    __builtin_amdgcn_wave_barrier();
    float a0 = 0.f, a1 = 0.f;
    #pragma unroll
    for (int i = 0; i < 16; ++i) {
      const float hv = hbS[wl][i];
      a0 += hv * ws2[f*256 + i*16 + o2];
      a1 += hv * ws2[f*256 + i*16 + o2 + 1];
    }
    hwS[wl][f*16 + o2] = a0; hwS[wl][f*16 + o2 + 1] = a1;
    if (lane < 16) {
      float s = 0.f;
      #pragma unroll
      for (int i = 0; i < 16; ++i) s += hbS[wl][i] * bs2[i*16 + lane];
      hbS[wl][16 + lane] = s;
    }
    __builtin_amdgcn_wave_barrier();
    const float4 mb = *reinterpret_cast<const float4*>(&hbS[wl][16 + q*4]);
    for (int j0 = 0; j0 < deg; j0 += 16) {
      const int jj = j0 + el;
      const bool act = (jj < deg);
      const int e = act ? elist[st + jj] : elist[st];
      const int d = act ? edst[e] : 0;
      const float4 ea0 = *reinterpret_cast<const float4*>(&ea[(size_t)e*8]);
      const float4 ea1 = *reinterpret_cast<const float4*>(&ea[(size_t)e*8 + 4]);
      const float ef[8] = {ea0.x, ea0.y, ea0.z, ea0.w, ea1.x, ea1.y, ea1.z, ea1.w};
      float4 m = mb;
      #pragma unroll
      for (int ff = 0; ff < 8; ++ff) {
        const float4 hv = *reinterpret_cast<const float4*>(&hwS[wl][ff*16 + q*4]);
        m.x += ef[ff]*hv.x; m.y += ef[ff]*hv.y; m.z += ef[ff]*hv.z; m.w += ef[ff]*hv.w;
      }
      if (act) {
        float* dst = &agg[(size_t)d*16 + q*4];
        atomAddF(dst+0, m.x); atomAddF(dst+1, m.y);
        atomAddF(dst+2, m.z); atomAddF(dst+3, m.w);
      }
      __builtin_amdgcn_wave_barrier();
    }
  }
}

// ---------------- K7: h2 = bn1(h1)@root2 + bias2 + agg/max(indeg,1); BN2 stats ----------------
__global__ __launch_bounds__(256) void k7_node2(const float* __restrict__ h1,
    const float* __restrict__ root2, const float* __restrict__ bias2,
    const float* __restrict__ agg, const float* __restrict__ indeg,
    float* __restrict__ h2, float* __restrict__ stats) {
  __shared__ float rt[256];
  __shared__ float red[2][16][17];
  __shared__ float sc[16], sh[16];
  rt[threadIdx.x] = root2[threadIdx.x];
  if (threadIdx.x < 16) { sc[threadIdx.x] = stats[32+threadIdx.x]; sh[threadIdx.x] = stats[48+threadIdx.x]; }
  const int o = threadIdx.x & 15, nl = threadIdx.x >> 4;
  const float bo = bias2[o];
  float s1 = 0.f, s2 = 0.f;
  __syncthreads();
  for (int n = blockIdx.x*16 + nl; n < NN; n += gridDim.x*16) {
    float acc = bo;
    #pragma unroll
    for (int i = 0; i < 16; ++i) {
      const float hbn = h1[(size_t)n*16 + i]*sc[i] + sh[i];
      acc += hbn * rt[i*16 + o];
    }
    acc += agg[(size_t)n*16 + o] / fmaxf(indeg[n], 1.0f);
    h2[(size_t)n*16 + o] = acc;
    s1 += acc; s2 += acc*acc;
  }
  red[0][nl][o] = s1; red[1][nl][o] = s2;
  __syncthreads();
  for (int step = 8; step > 0; step >>= 1) {
    if (nl < step) {
      red[0][nl][o] += red[0][nl+step][o];
      red[1][nl][o] += red[1][nl+step][o];
    }
    __syncthreads();
  }
  if (nl == 0) { atomAddF(&stats[64+o], red[0][0][o]); atomAddF(&stats[80+o], red[1][0][o]); }
}

__global__ void k8_fin2(const float* __restrict__ g, const float* __restrict__ b,
                        float* __restrict__ stats) {
  const int o = threadIdx.x;
  if (o < 16) {
    const float mean = stats[64+o] / (float)NN;
    const float var  = stats[80+o] / (float)NN - mean*mean;
    const float sc   = g[o] * rsqrtf(var + EPS);
    stats[96+o]  = sc;
    stats[112+o] = b[o] - mean*sc;
  }
}

__global__ __launch_bounds__(256) void k9_pool(const float* __restrict__ h2,
    const int* __restrict__ batch, float* __restrict__ stats) {
  const int o = threadIdx.x & 15, nl = threadIdx.x >> 4;
  const float sc = stats[96+o], sh = stats[112+o];
  float* gsum = &stats[128];
  float* gcnt = &stats[1152];
  for (int n = blockIdx.x*16 + nl; n < NN; n += gridDim.x*16) {
    const float v = h2[(size_t)n*16 + o]*sc + sh;
    const int g = batch[n];
    atomAddF(&gsum[g*16 + o], v);
    if (o == 0) atomAddF(&gcnt[g], 1.0f);
  }
}

__global__ __launch_bounds__(128) void k10_head(const float* __restrict__ stats,
    const float* __restrict__ w1, const float* __restrict__ b1,
    const float* __restrict__ w2, const float* __restrict__ b2,
    float* __restrict__ out) {
  __shared__ float gm[16];
  __shared__ float a[128];
  __shared__ float l[10];
  __shared__ float mls[2];
  const int g = blockIdx.x, j = threadIdx.x;
  if (j < 16) gm[j] = stats[128 + g*16 + j] / fmaxf(stats[1152+g], 1.0f);
  __syncthreads();
  float s = b1[j];
  #pragma unroll
  for (int o = 0; o < 16; ++o) s += gm[o]*w1[o*128 + j];
  a[j] = fmaxf(s, 0.f);
  __syncthreads();
  if (j < 10) {
    float t = b2[j];
    #pragma unroll 16
    for (int k = 0; k < 128; ++k) t += a[k]*w2[k*10 + j];
    l[j] = t;
  }
  __syncthreads();
  if (j == 0) {
    float m = l[0];
    for (int c = 1; c < 10; ++c) m = fmaxf(m, l[c]);
    float se = 0.f;
    for (int c = 0; c < 10; ++c) se += expf(l[c]-m);
    mls[0] = m; mls[1] = logf(se);
  }
  __syncthreads();
  if (j < 10) out[g*10 + j] = l[j] - mls[0] - mls[1];
}

extern "C" void kernel_launch(void* const* d_in, const int* in_sizes, int n_in,
                              void* d_out, int out_size, void* d_ws, size_t ws_size,
                              hipStream_t stream) {
  const float* x      = (const float*)d_in[0];
  const int*   esrc   = (const int*)  d_in[1];
  const int*   edst   = (const int*)  d_in[2];
  const float* ea     = (const float*)d_in[3];
  const int*   batch  = (const int*)  d_in[4];
  const float* en1_w1 = (const float*)d_in[5];
  const float* en1_b1 = (const float*)d_in[6];
  const float* en1_w2 = (const float*)d_in[7];
  const float* en1_b2 = (const float*)d_in[8];
  const float* root1  = (const float*)d_in[9];
  const float* bias1  = (const float*)d_in[10];
  const float* bn1_g  = (const float*)d_in[11];
  const float* bn1_b  = (const float*)d_in[12];
  const float* en2_w  = (const float*)d_in[13];
  const float* en2_b  = (const float*)d_in[14];
  const float* root2  = (const float*)d_in[15];
  const float* bias2  = (const float*)d_in[16];
  const float* bn2_g  = (const float*)d_in[17];
  const float* bn2_b  = (const float*)d_in[18];
  const float* mlp_w1 = (const float*)d_in[19];
  const float* mlp_b1 = (const float*)d_in[20];
  const float* mlp_w2 = (const float*)d_in[21];
  const float* mlp_b2 = (const float*)d_in[22];
  float* out = (float*)d_out;
  float* ws  = (float*)d_ws;

  float* xwbuf = ws + OFS_XWBUF;
  float* xb2   = ws + OFS_XB2;
  float* agg   = ws + OFS_AGG;
  float* indeg = ws + OFS_INDEG;
  float* stats = ws + OFS_STATS;
  float* h1    = ws + OFS_H1;
  float* h2    = ws + OFS_H2;
  int*   elist = (int*)(ws + OFS_ELIST);
  int*   off   = (int*)(ws + OFS_OFF);
  int*   outc  = (int*)(ws + OFS_OUTC);

  hipMemsetAsync(outc,  0, 25600*sizeof(int),   stream);
  hipMemsetAsync(indeg, 0, 25600*sizeof(float), stream);
  hipMemsetAsync(agg,   0, (size_t)NN*16*sizeof(float), stream);
  hipMemsetAsync(stats, 0, 2048*sizeof(float),  stream);

  // CSR build
  hipLaunchKernelGGL(k0_hist, dim3(1024), dim3(256),  0, stream, esrc, edst, outc, indeg);
  hipLaunchKernelGGL(k0_scan, dim3(1),    dim3(1024), 0, stream, outc, off);
  hipLaunchKernelGGL(k0_fill, dim3(1024), dim3(256),  0, stream, esrc, outc, off, elist);

  // layer 1, chunked over nodes
  const int nb1 = (CHUNK + 15) / 16;
  hipLaunchKernelGGL(k1_xw,  dim3(nb1),  dim3(256), 0, stream, x, en1_w2, en1_b2, xwbuf, xb2, 0, CHUNK);
  hipLaunchKernelGGL(k2_csr, dim3(1024), dim3(256), 0, stream, ea, edst, en1_w1, en1_b1,
                     xwbuf, xb2, off, elist, agg, 0, CHUNK);
  hipLaunchKernelGGL(k1_xw,  dim3(nb1),  dim3(256), 0, stream, x, en1_w2, en1_b2, xwbuf, xb2, CHUNK, NN);
  hipLaunchKernelGGL(k2_csr, dim3(1024), dim3(256), 0, stream, ea, edst, en1_w1, en1_b1,
                     xwbuf, xb2, off, elist, agg, CHUNK, NN);

  hipLaunchKernelGGL(k3_node1, dim3(256), dim3(256), 0, stream, x, root1, bias1, agg, indeg, h1, stats);
  hipLaunchKernelGGL(k4_fin1,  dim3(1),   dim3(64),  0, stream, bn1_g, bn1_b, stats);

  // layer 2
  hipMemsetAsync(agg, 0, (size_t)NN*16*sizeof(float), stream);
  hipLaunchKernelGGL(k6_csr,   dim3(1024), dim3(256), 0, stream, ea, edst, h1, stats,
                     en2_w, en2_b, off, elist, agg);
  hipLaunchKernelGGL(k7_node2, dim3(256),  dim3(256), 0, stream, h1, root2, bias2, agg, indeg, h2, stats);
  hipLaunchKernelGGL(k8_fin2,  dim3(1),    dim3(64),  0, stream, bn2_g, bn2_b, stats);

  // pool + head
  hipLaunchKernelGGL(k9_pool,  dim3(256), dim3(256), 0, stream, h2, batch, stats);
  hipLaunchKernelGGL(k10_head, dim3(64),  dim3(128), 0, stream, stats, mlp_w1, mlp_b1, mlp_w2, mlp_b2, out);
}

// Round 3
// 419.949 us; speedup vs baseline: 1.5649x; 1.4524x over previous
//
#include <hip/hip_runtime.h>

// ---- problem constants ----
#define NN 25000          // nodes
#define NE 400000         // edges
#define NGR 64            // graphs
#define CHUNK 12500       // nodes per xw-buffer chunk
// IN=HID=OUT=16, EF=8, EH=64, NH=128, NC=10
#define EPS 1e-5f

// ---- workspace layout (floats) ----
static const size_t OFS_XWBUF = 0;          // CHUNK*1024 = 12,800,000
static const size_t OFS_H1    = 0;          // N*16 (alias, written K3 after xwbuf dead)
static const size_t OFS_XB2   = 12800000;   // N*16
static const size_t OFS_AGG   = 13200000;   // N*16 (layer1 then re-zeroed for layer2)
static const size_t OFS_INDEG = 13600000;   // 25600 (float)
static const size_t OFS_STATS = 13625600;   // 2048 used (25600 reserved)
static const size_t OFS_ELIST = 13651200;   // NE (int)
static const size_t OFS_OFF   = 14051200;   // 25600 (int)
static const size_t OFS_OUTC  = 14076800;   // 25600 (int; reused as fill cursor)
// stats: [0]sum1 [16]sumsq1 [32]scale1 [48]shift1 [64]sum2 [80]sumsq2
//        [96]scale2 [112]shift2 [128]gsum_raw(64*16) [1152]gcnt(64)

__device__ __forceinline__ void atomAddF(float* p, float v) {
  unsafeAtomicAdd(p, v);   // HW global_atomic_add_f32 on gfx950
}

// ---------------- CSR build ----------------
__global__ __launch_bounds__(256) void k0_hist(const int* __restrict__ esrc,
    const int* __restrict__ edst, int* __restrict__ outc, float* __restrict__ indeg) {
  for (int e = blockIdx.x*blockDim.x + threadIdx.x; e < NE; e += gridDim.x*blockDim.x) {
    atomicAdd(&outc[esrc[e]], 1);
    atomAddF(&indeg[edst[e]], 1.0f);
  }
}

__global__ __launch_bounds__(1024) void k0_scan(int* __restrict__ outc, int* __restrict__ off) {
  __shared__ int ps[1024];
  const int t = threadIdx.x;
  const int base = t * 25;            // 1024*25 = 25600 >= 25001
  int s = 0;
  for (int k = 0; k < 25; ++k) { int i = base + k; if (i < NN) s += outc[i]; }
  ps[t] = s; __syncthreads();
  for (int st = 1; st < 1024; st <<= 1) {
    int v = (t >= st) ? ps[t - st] : 0;
    __syncthreads();
    ps[t] += v;
    __syncthreads();
  }
  int run = (t > 0) ? ps[t-1] : 0;
  for (int k = 0; k < 25; ++k) {
    int i = base + k;
    if (i < NN)       { off[i] = run; run += outc[i]; outc[i] = 0; }  // zero -> cursor
    else if (i == NN) { off[i] = run; }
  }
}

__global__ __launch_bounds__(256) void k0_fill(const int* __restrict__ esrc,
    int* __restrict__ cur, const int* __restrict__ off, int* __restrict__ elist) {
  for (int e = blockIdx.x*blockDim.x + threadIdx.x; e < NE; e += gridDim.x*blockDim.x) {
    const int s = esrc[e];
    const int p = atomicAdd(&cur[s], 1);
    elist[off[s] + p] = e;
  }
}

// ---------------- K1: per-node weight precompute (chunked) ----------------
__global__ __launch_bounds__(256) void k1_xw(const float* __restrict__ x,
    const float* __restrict__ w2, const float* __restrict__ b2,
    float* __restrict__ xwbuf, float* __restrict__ xb2, int n0, int n1) {
  __shared__ float xs[16][17];
  const int t = threadIdx.x;
  const int h = t >> 2, og = (t & 3) * 4;
  const int nbase = n0 + blockIdx.x * 16;
  if (nbase >= n1) return;
  {
    const int n = nbase + (t >> 4), i = t & 15;
    xs[t >> 4][i] = (n < n1) ? x[(size_t)n*16 + i] : 0.f;
  }
  __syncthreads();
  float4 acc[16];
  #pragma unroll
  for (int n = 0; n < 16; ++n) acc[n] = make_float4(0.f,0.f,0.f,0.f);
  #pragma unroll
  for (int i = 0; i < 16; ++i) {
    const float4 w = *reinterpret_cast<const float4*>(&w2[h*256 + i*16 + og]);
    #pragma unroll
    for (int n = 0; n < 16; ++n) {
      const float xv = xs[n][i];
      acc[n].x += xv*w.x; acc[n].y += xv*w.y; acc[n].z += xv*w.z; acc[n].w += xv*w.w;
    }
  }
  #pragma unroll
  for (int n = 0; n < 16; ++n) {
    const int nn = nbase + n;
    if (nn < n1)
      *reinterpret_cast<float4*>(&xwbuf[(size_t)(nn - n0)*1024 + h*16 + og]) = acc[n];
  }
  {
    const int n = nbase + (t >> 4), o = t & 15;
    if (n < n1) {
      float s = 0.f;
      #pragma unroll
      for (int i = 0; i < 16; ++i) s += xs[t >> 4][i] * b2[i*16 + o];
      xb2[(size_t)n*16 + o] = s;
    }
  }
}

// ---------------- K2: layer-1 edge pass, CSR-by-src, xw staged in LDS ----------------
__global__ __launch_bounds__(256) void k2_csr(const float* __restrict__ ea,
    const int* __restrict__ edst,
    const float* __restrict__ w1, const float* __restrict__ b1,
    const float* __restrict__ xwbuf, const float* __restrict__ xb2,
    const int* __restrict__ off, const int* __restrict__ elist,
    float* __restrict__ agg, int n0, int n1) {
  __shared__ float w1s[512];
  __shared__ float b1s[64];
  __shared__ float xwS[4][1024];
  __shared__ float rs[4][16][68];
  for (int idx = threadIdx.x; idx < 512; idx += 256) w1s[idx] = w1[idx];
  if (threadIdx.x < 64) b1s[threadIdx.x] = b1[threadIdx.x];
  __syncthreads();
  const int lane = threadIdx.x & 63, wl = threadIdx.x >> 6;
  const int el = lane >> 2, q = lane & 3;
  const int gw = blockIdx.x*4 + wl, nw = gridDim.x*4;
  float* xw = xwS[wl];
  float (*rsw)[68] = rs[wl];

  for (int n = n0 + gw; n < n1; n += nw) {
    const int st = off[n];
    const int deg = off[n+1] - st;
    if (deg == 0) continue;
    const float4* src = reinterpret_cast<const float4*>(&xwbuf[(size_t)(n - n0)*1024]);
    #pragma unroll
    for (int j = 0; j < 4; ++j) {
      const float4 v = src[j*64 + lane];
      *reinterpret_cast<float4*>(&xw[j*256 + lane*4]) = v;
    }
    const float4 mb = *reinterpret_cast<const float4*>(&xb2[(size_t)n*16 + q*4]);
    __builtin_amdgcn_wave_barrier();

    for (int j0 = 0; j0 < deg; j0 += 16) {
      const int jj = j0 + el;
      const bool act = (jj < deg);
      const int e = act ? elist[st + jj] : elist[st];
      const int d = act ? edst[e] : 0;
      const float4 ea0 = *reinterpret_cast<const float4*>(&ea[(size_t)e*8]);
      const float4 ea1 = *reinterpret_cast<const float4*>(&ea[(size_t)e*8 + 4]);
      const float eav[8] = {ea0.x, ea0.y, ea0.z, ea0.w, ea1.x, ea1.y, ea1.z, ea1.w};
      #pragma unroll
      for (int g = 0; g < 4; ++g) {
        float4 r4 = *reinterpret_cast<const float4*>(&b1s[q*16 + g*4]);
        #pragma unroll
        for (int f = 0; f < 8; ++f) {
          const float4 wv = *reinterpret_cast<const float4*>(&w1s[f*64 + q*16 + g*4]);
          r4.x += eav[f]*wv.x; r4.y += eav[f]*wv.y;
          r4.z += eav[f]*wv.z; r4.w += eav[f]*wv.w;
        }
        r4.x = fmaxf(r4.x, 0.f); r4.y = fmaxf(r4.y, 0.f);
        r4.z = fmaxf(r4.z, 0.f); r4.w = fmaxf(r4.w, 0.f);
        *reinterpret_cast<float4*>(&rsw[el][q*16 + g*4]) = r4;
      }
      __builtin_amdgcn_wave_barrier();
      float4 m = mb;
      #pragma unroll
      for (int h0 = 0; h0 < 16; ++h0) {
        const float4 rv = *reinterpret_cast<const float4*>(&rsw[el][h0*4]);
        const float4 x0 = *reinterpret_cast<const float4*>(&xw[(h0*4+0)*16 + q*4]);
        const float4 x1 = *reinterpret_cast<const float4*>(&xw[(h0*4+1)*16 + q*4]);
        const float4 x2 = *reinterpret_cast<const float4*>(&xw[(h0*4+2)*16 + q*4]);
        const float4 x3 = *reinterpret_cast<const float4*>(&xw[(h0*4+3)*16 + q*4]);
        m.x += rv.x*x0.x + rv.y*x1.x + rv.z*x2.x + rv.w*x3.x;
        m.y += rv.x*x0.y + rv.y*x1.y + rv.z*x2.y + rv.w*x3.y;
        m.z += rv.x*x0.z + rv.y*x1.z + rv.z*x2.z + rv.w*x3.z;
        m.w += rv.x*x0.w + rv.y*x1.w + rv.z*x2.w + rv.w*x3.w;
      }
      if (act) {
        float* dst = &agg[(size_t)d*16 + q*4];
        atomAddF(dst+0, m.x); atomAddF(dst+1, m.y);
        atomAddF(dst+2, m.z); atomAddF(dst+3, m.w);
      }
      __builtin_amdgcn_wave_barrier();
    }
  }
}

// ---------------- K3: h1 = x@root1 + agg/max(indeg,1) + bias1; BN1 stats ----------------
__global__ __launch_bounds__(256) void k3_node1(const float* __restrict__ x,
    const float* __restrict__ root1, const float* __restrict__ bias1,
    const float* __restrict__ agg, const float* __restrict__ indeg,
    float* __restrict__ h1, float* __restrict__ stats) {
  __shared__ float rt[256];
  __shared__ float red[2][16][17];
  rt[threadIdx.x] = root1[threadIdx.x];
  const int o = threadIdx.x & 15, nl = threadIdx.x >> 4;
  const float bo = bias1[o];
  float s1 = 0.f, s2 = 0.f;
  __syncthreads();
  for (int n = blockIdx.x*16 + nl; n < NN; n += gridDim.x*16) {
    float acc = bo;
    #pragma unroll
    for (int i = 0; i < 16; ++i) acc += x[(size_t)n*16 + i] * rt[i*16 + o];
    acc += agg[(size_t)n*16 + o] / fmaxf(indeg[n], 1.0f);
    h1[(size_t)n*16 + o] = acc;
    s1 += acc; s2 += acc*acc;
  }
  red[0][nl][o] = s1; red[1][nl][o] = s2;
  __syncthreads();
  for (int step = 8; step > 0; step >>= 1) {
    if (nl < step) {
      red[0][nl][o] += red[0][nl+step][o];
      red[1][nl][o] += red[1][nl+step][o];
    }
    __syncthreads();
  }
  if (nl == 0) { atomAddF(&stats[o], red[0][0][o]); atomAddF(&stats[16+o], red[1][0][o]); }
}

__global__ void k4_fin1(const float* __restrict__ g, const float* __restrict__ b,
                        float* __restrict__ stats) {
  const int o = threadIdx.x;
  if (o < 16) {
    const float mean = stats[o] / (float)NN;
    const float var  = stats[16+o] / (float)NN - mean*mean;
    const float sc   = g[o] * rsqrtf(var + EPS);
    stats[32+o] = sc;
    stats[48+o] = b[o] - mean*sc;
  }
}

// ---------------- K6: layer-2 edge pass, CSR-by-src, hw computed per node ----------------
__global__ __launch_bounds__(256) void k6_csr(const float* __restrict__ ea,
    const int* __restrict__ edst,
    const float* __restrict__ h1, const float* __restrict__ stats,
    const float* __restrict__ w, const float* __restrict__ bvec,
    const int* __restrict__ off, const int* __restrict__ elist,
    float* __restrict__ agg) {
  __shared__ float ws2[2048];
  __shared__ float bs2[256];
  __shared__ float hwS[4][128];
  __shared__ float hbS[4][32];   // [0..15] hbn, [16..31] hb
  for (int idx = threadIdx.x; idx < 2048; idx += 256) ws2[idx] = w[idx];
  bs2[threadIdx.x] = bvec[threadIdx.x];
  __syncthreads();
  const int lane = threadIdx.x & 63, wl = threadIdx.x >> 6;
  const int el = lane >> 2, q = lane & 3;
  const int f = lane >> 3, o2 = (lane & 7) * 2;
  const int gw = blockIdx.x*4 + wl, nw = gridDim.x*4;
  for (int n = gw; n < NN; n += nw) {
    const int st = off[n];
    const int deg = off[n+1] - st;
    if (deg == 0) continue;
    if (lane < 16)
      hbS[wl][lane] = h1[(size_t)n*16 + lane]*stats[32+lane] + stats[48+lane];
    __builtin_amdgcn_wave_barrier();
    float a0 = 0.f, a1 = 0.f;
    #pragma unroll
    for (int i = 0; i < 16; ++i) {
      const float hv = hbS[wl][i];
      a0 += hv * ws2[f*256 + i*16 + o2];
      a1 += hv * ws2[f*256 + i*16 + o2 + 1];
    }
    hwS[wl][f*16 + o2] = a0; hwS[wl][f*16 + o2 + 1] = a1;
    if (lane < 16) {
      float s = 0.f;
      #pragma unroll
      for (int i = 0; i < 16; ++i) s += hbS[wl][i] * bs2[i*16 + lane];
      hbS[wl][16 + lane] = s;
    }
    __builtin_amdgcn_wave_barrier();
    const float4 mb = *reinterpret_cast<const float4*>(&hbS[wl][16 + q*4]);
    for (int j0 = 0; j0 < deg; j0 += 16) {
      const int jj = j0 + el;
      const bool act = (jj < deg);
      const int e = act ? elist[st + jj] : elist[st];
      const int d = act ? edst[e] : 0;
      const float4 ea0 = *reinterpret_cast<const float4*>(&ea[(size_t)e*8]);
      const float4 ea1 = *reinterpret_cast<const float4*>(&ea[(size_t)e*8 + 4]);
      const float ef[8] = {ea0.x, ea0.y, ea0.z, ea0.w, ea1.x, ea1.y, ea1.z, ea1.w};
      float4 m = mb;
      #pragma unroll
      for (int ff = 0; ff < 8; ++ff) {
        const float4 hv = *reinterpret_cast<const float4*>(&hwS[wl][ff*16 + q*4]);
        m.x += ef[ff]*hv.x; m.y += ef[ff]*hv.y; m.z += ef[ff]*hv.z; m.w += ef[ff]*hv.w;
      }
      if (act) {
        float* dst = &agg[(size_t)d*16 + q*4];
        atomAddF(dst+0, m.x); atomAddF(dst+1, m.y);
        atomAddF(dst+2, m.z); atomAddF(dst+3, m.w);
      }
      __builtin_amdgcn_wave_barrier();
    }
  }
}

// ---------------- K7: h2 + BN2 stats + fused raw pooling (contiguous slabs) ----------------
#define PB 98   // nodes per block; 256*98 = 25088 >= 25000
__global__ __launch_bounds__(256) void k7_node2(const float* __restrict__ h1,
    const float* __restrict__ root2, const float* __restrict__ bias2,
    const float* __restrict__ agg, const float* __restrict__ indeg,
    const int* __restrict__ batch, float* __restrict__ stats) {
  __shared__ float rt[256];
  __shared__ float red[2][16][17];
  __shared__ float sc[16], sh[16];
  __shared__ float pool[64*17];   // [g*17 + o], col 16 = count
  rt[threadIdx.x] = root2[threadIdx.x];
  if (threadIdx.x < 16) { sc[threadIdx.x] = stats[32+threadIdx.x]; sh[threadIdx.x] = stats[48+threadIdx.x]; }
  for (int idx = threadIdx.x; idx < 64*17; idx += 256) pool[idx] = 0.f;
  const int o = threadIdx.x & 15, nl = threadIdx.x >> 4;
  const float bo = bias2[o];
  const int nstart = blockIdx.x * PB;
  const int nend = (nstart + PB < NN) ? nstart + PB : NN;
  float s1 = 0.f, s2 = 0.f;
  __syncthreads();
  for (int n = nstart + nl; n < nend; n += 16) {
    float acc = bo;
    #pragma unroll
    for (int i = 0; i < 16; ++i) {
      const float hbn = h1[(size_t)n*16 + i]*sc[i] + sh[i];
      acc += hbn * rt[i*16 + o];
    }
    acc += agg[(size_t)n*16 + o] / fmaxf(indeg[n], 1.0f);
    s1 += acc; s2 += acc*acc;
    const int g = batch[n];
    atomicAdd(&pool[g*17 + o], acc);          // LDS ds_add_f32
    if (o == 0) atomicAdd(&pool[g*17 + 16], 1.0f);
  }
  red[0][nl][o] = s1; red[1][nl][o] = s2;
  __syncthreads();
  for (int step = 8; step > 0; step >>= 1) {
    if (nl < step) {
      red[0][nl][o] += red[0][nl+step][o];
      red[1][nl][o] += red[1][nl+step][o];
    }
    __syncthreads();
  }
  if (nl == 0) { atomAddF(&stats[64+o], red[0][0][o]); atomAddF(&stats[80+o], red[1][0][o]); }
  // flush per-graph partials (only ~2 graphs per block are nonzero)
  for (int idx = threadIdx.x; idx < 64*17; idx += 256) {
    const float v = pool[idx];
    if (v != 0.f) {
      const int g = idx / 17, c = idx - g*17;
      atomAddF((c < 16) ? &stats[128 + g*16 + c] : &stats[1152 + g], v);
    }
  }
}

__global__ void k8_fin2(const float* __restrict__ g, const float* __restrict__ b,
                        float* __restrict__ stats) {
  const int o = threadIdx.x;
  if (o < 16) {
    const float mean = stats[64+o] / (float)NN;
    const float var  = stats[80+o] / (float)NN - mean*mean;
    const float sc   = g[o] * rsqrtf(var + EPS);
    stats[96+o]  = sc;
    stats[112+o] = b[o] - mean*sc;
  }
}

// ---------------- K10: graph mean (raw) -> BN2 affine -> MLP head -> log_softmax ----------------
__global__ __launch_bounds__(128) void k10_head(const float* __restrict__ stats,
    const float* __restrict__ w1, const float* __restrict__ b1,
    const float* __restrict__ w2, const float* __restrict__ b2,
    float* __restrict__ out) {
  __shared__ float gm[16];
  __shared__ float a[128];
  __shared__ float l[10];
  __shared__ float mls[2];
  const int g = blockIdx.x, j = threadIdx.x;
  if (j < 16) {
    const float cnt = fmaxf(stats[1152 + g], 1.0f);
    gm[j] = (stats[128 + g*16 + j] / cnt) * stats[96 + j] + stats[112 + j];
  }
  __syncthreads();
  float s = b1[j];
  #pragma unroll
  for (int o = 0; o < 16; ++o) s += gm[o]*w1[o*128 + j];
  a[j] = fmaxf(s, 0.f);
  __syncthreads();
  if (j < 10) {
    float t = b2[j];
    #pragma unroll 16
    for (int k = 0; k < 128; ++k) t += a[k]*w2[k*10 + j];
    l[j] = t;
  }
  __syncthreads();
  if (j == 0) {
    float m = l[0];
    for (int c = 1; c < 10; ++c) m = fmaxf(m, l[c]);
    float se = 0.f;
    for (int c = 0; c < 10; ++c) se += expf(l[c]-m);
    mls[0] = m; mls[1] = logf(se);
  }
  __syncthreads();
  if (j < 10) out[g*10 + j] = l[j] - mls[0] - mls[1];
}

extern "C" void kernel_launch(void* const* d_in, const int* in_sizes, int n_in,
                              void* d_out, int out_size, void* d_ws, size_t ws_size,
                              hipStream_t stream) {
  const float* x      = (const float*)d_in[0];
  const int*   esrc   = (const int*)  d_in[1];
  const int*   edst   = (const int*)  d_in[2];
  const float* ea     = (const float*)d_in[3];
  const int*   batch  = (const int*)  d_in[4];
  const float* en1_w1 = (const float*)d_in[5];
  const float* en1_b1 = (const float*)d_in[6];
  const float* en1_w2 = (const float*)d_in[7];
  const float* en1_b2 = (const float*)d_in[8];
  const float* root1  = (const float*)d_in[9];
  const float* bias1  = (const float*)d_in[10];
  const float* bn1_g  = (const float*)d_in[11];
  const float* bn1_b  = (const float*)d_in[12];
  const float* en2_w  = (const float*)d_in[13];
  const float* en2_b  = (const float*)d_in[14];
  const float* root2  = (const float*)d_in[15];
  const float* bias2  = (const float*)d_in[16];
  const float* bn2_g  = (const float*)d_in[17];
  const float* bn2_b  = (const float*)d_in[18];
  const float* mlp_w1 = (const float*)d_in[19];
  const float* mlp_b1 = (const float*)d_in[20];
  const float* mlp_w2 = (const float*)d_in[21];
  const float* mlp_b2 = (const float*)d_in[22];
  float* out = (float*)d_out;
  float* ws  = (float*)d_ws;

  float* xwbuf = ws + OFS_XWBUF;
  float* xb2   = ws + OFS_XB2;
  float* agg   = ws + OFS_AGG;
  float* indeg = ws + OFS_INDEG;
  float* stats = ws + OFS_STATS;
  float* h1    = ws + OFS_H1;
  int*   elist = (int*)(ws + OFS_ELIST);
  int*   off   = (int*)(ws + OFS_OFF);
  int*   outc  = (int*)(ws + OFS_OUTC);

  hipMemsetAsync(outc,  0, 25600*sizeof(int),   stream);
  hipMemsetAsync(indeg, 0, 25600*sizeof(float), stream);
  hipMemsetAsync(agg,   0, (size_t)NN*16*sizeof(float), stream);
  hipMemsetAsync(stats, 0, 2048*sizeof(float),  stream);

  // CSR build
  hipLaunchKernelGGL(k0_hist, dim3(1024), dim3(256),  0, stream, esrc, edst, outc, indeg);
  hipLaunchKernelGGL(k0_scan, dim3(1),    dim3(1024), 0, stream, outc, off);
  hipLaunchKernelGGL(k0_fill, dim3(1024), dim3(256),  0, stream, esrc, outc, off, elist);

  // layer 1, chunked over nodes
  const int nb1 = (CHUNK + 15) / 16;
  hipLaunchKernelGGL(k1_xw,  dim3(nb1),  dim3(256), 0, stream, x, en1_w2, en1_b2, xwbuf, xb2, 0, CHUNK);
  hipLaunchKernelGGL(k2_csr, dim3(1024), dim3(256), 0, stream, ea, edst, en1_w1, en1_b1,
                     xwbuf, xb2, off, elist, agg, 0, CHUNK);
  hipLaunchKernelGGL(k1_xw,  dim3(nb1),  dim3(256), 0, stream, x, en1_w2, en1_b2, xwbuf, xb2, CHUNK, NN);
  hipLaunchKernelGGL(k2_csr, dim3(1024), dim3(256), 0, stream, ea, edst, en1_w1, en1_b1,
                     xwbuf, xb2, off, elist, agg, CHUNK, NN);

  hipLaunchKernelGGL(k3_node1, dim3(256), dim3(256), 0, stream, x, root1, bias1, agg, indeg, h1, stats);
  hipLaunchKernelGGL(k4_fin1,  dim3(1),   dim3(64),  0, stream, bn1_g, bn1_b, stats);

  // layer 2
  hipMemsetAsync(agg, 0, (size_t)NN*16*sizeof(float), stream);
  hipLaunchKernelGGL(k6_csr,   dim3(1024), dim3(256), 0, stream, ea, edst, h1, stats,
                     en2_w, en2_b, off, elist, agg);
  hipLaunchKernelGGL(k7_node2, dim3(256),  dim3(256), 0, stream, h1, root2, bias2, agg, indeg,
                     batch, stats);
  hipLaunchKernelGGL(k8_fin2,  dim3(1),    dim3(64),  0, stream, bn2_g, bn2_b, stats);

  // head
  hipLaunchKernelGGL(k10_head, dim3(64),  dim3(128), 0, stream, stats, mlp_w1, mlp_b1, mlp_w2, mlp_b2, out);
}